// Round 12
// baseline (325.302 us; speedup 1.0000x reference)
//
#include <hip/hip_runtime.h>
#include <hip/hip_bf16.h>
#include <stdint.h>

typedef short bf16x8 __attribute__((ext_vector_type(8)));
typedef float f32x4 __attribute__((ext_vector_type(4)));

#define DEVI static __device__ __forceinline__

DEVI ushort f2bf(float f) {
  union { float f; uint32_t u; } v; v.f = f;
  uint32_t u = v.u;
  return (ushort)((u + 0x7fffu + ((u >> 16) & 1u)) >> 16);
}

DEVI uint cvtpk(float lo, float hi) {
  uint r;
  asm("v_cvt_pk_bf16_f32 %0, %1, %2" : "=v"(r) : "v"(lo), "v"(hi));
  return r;
}

DEVI void gload16(const void* g, void* l) {
  __builtin_amdgcn_global_load_lds((const __attribute__((address_space(1))) void*)g,
                                   (__attribute__((address_space(3))) void*)l,
                                   16, 0, 0);
}

#define SB() __builtin_amdgcn_sched_barrier(0)
#define BAR() __builtin_amdgcn_s_barrier()
#define MFMA(a, b, c) __builtin_amdgcn_mfma_f32_16x16x32_bf16((a), (b), (c), 0, 0, 0)

// Pair-interleaved 8-slot swizzle for BK=32 tiles (rows of 64B):
// pair-region (r>>1) = 128B with 8 slots of 16B; logical slot s = k8*2 + (r&1),
// physical = s ^ ((r>>1)&7). Identity: pair_frag_off(pair_src_row(c)) == c*8.
DEVI int pair_src_row(int c, int* k8) {       // c = linear chunk index
  int pair = c >> 3;
  int s = (c & 7) ^ (pair & 7);
  *k8 = s >> 1;
  return pair * 2 + (s & 1);
}
DEVI int pair_frag_off(int r, int k8) {       // ushort offset within region
  int p = (k8 * 2 + (r & 1)) ^ ((r >> 1) & 7);
  return (r >> 1) * 64 + p * 8;
}

// ---------------- Wq fold + transpose via LDS tile (r9-proven) ----------------
__global__ __launch_bounds__(256) void fold_t(
    const float* __restrict__ W, const float* __restrict__ up,
    const float* __restrict__ down, ushort* __restrict__ outT, float scale)
{
  __shared__ ushort tile[64][66];
  const int o0 = blockIdx.x * 64, i0 = blockIdx.y * 64;
  const int lo = threadIdx.x >> 6;
  const int li = threadIdx.x & 63;
#pragma unroll
  for (int r = 0; r < 16; ++r) {
    int o = o0 + r * 4 + lo;
    int i = i0 + li;
    float v = W[(long)o * 1280 + i];
#pragma unroll
    for (int q = 0; q < 4; ++q) v += up[o * 4 + q] * down[q * 1280 + i];
    tile[li][r * 4 + lo] = f2bf(v * scale);
  }
  __syncthreads();
#pragma unroll
  for (int r = 0; r < 16; ++r) {
    int i = i0 + r * 4 + lo;
    outT[(long)i * 1280 + o0 + li] = tile[r * 4 + lo][li];
  }
}

// ---------------- smalls: cvt_ehs | fold Wk/Wv/Wo | Nt pad (r9-proven) ----------------
__global__ __launch_bounds__(256) void smalls(
    const float* __restrict__ ehs, ushort* __restrict__ ehs_bf,
    const float* __restrict__ Wk, const float* __restrict__ k_up, const float* __restrict__ k_down,
    const float* __restrict__ Wv, const float* __restrict__ v_up, const float* __restrict__ v_down,
    ushort* __restrict__ Wkv,
    const float* __restrict__ Wo, const float* __restrict__ o_up, const float* __restrict__ o_down,
    ushort* __restrict__ Wo_bf, ushort* __restrict__ Nt)
{
  const int b = blockIdx.x;
  const int tid = threadIdx.x;
  if (b < 231) {
    int idx = b * 256 + tid;
    if (idx < 59136) {
      const float4* p = (const float4*)(ehs + (long)idx * 8);
      float4 a = p[0], c = p[1];
      union { ushort us[8]; uint4 v; } r;
      r.us[0] = f2bf(a.x); r.us[1] = f2bf(a.y); r.us[2] = f2bf(a.z); r.us[3] = f2bf(a.w);
      r.us[4] = f2bf(c.x); r.us[5] = f2bf(c.y); r.us[6] = f2bf(c.z); r.us[7] = f2bf(c.w);
      *(uint4*)(ehs_bf + (long)idx * 8) = r.v;
    }
  } else if (b < 4071) {
    int idx = (b - 231) * 256 + tid;
    int o = idx / 768, i = idx - o * 768;
    float v = Wk[idx];
#pragma unroll
    for (int q = 0; q < 4; ++q) v += k_up[o * 4 + q] * k_down[q * 768 + i];
    Wkv[idx] = f2bf(v);
  } else if (b < 7911) {
    int idx = (b - 4071) * 256 + tid;
    int o = idx / 768, i = idx - o * 768;
    float v = Wv[idx];
#pragma unroll
    for (int q = 0; q < 4; ++q) v += v_up[o * 4 + q] * v_down[q * 768 + i];
    Wkv[983040 + idx] = f2bf(v);
  } else if (b < 14311) {
    int idx = (b - 7911) * 256 + tid;
    int o = idx / 1280, i = idx - o * 1280;
    float v = Wo[idx];
#pragma unroll
    for (int q = 0; q < 4; ++q) v += o_up[o * 4 + q] * o_down[q * 1280 + i];
    Wo_bf[idx] = f2bf(v);
  } else {
    int idx = (b - 14311) * 256 + tid;
    int bb = idx / (1280 * 24);
    int rem = idx % (1280 * 24);
    int j = rem / 24, q = rem % 24;
    int h = q / 3, t = 77 + q % 3;
    Nt[(long)bb * 1280 * 640 + (long)j * 640 + h * 80 + t] = 0;
  }
}

// ---------------- small-GEMM body (128x128, BK=32) — proven ----------------

DEVI void gemm_bt_body(int bx, int by, int z,
    const ushort* __restrict__ A, long sA0, long sA1, int lda, int validM,
    const ushort* __restrict__ B, long sB0, long sB1, int ldb, int validN,
    float* __restrict__ C32, ushort* __restrict__ C16, long sC0, long sC1, int ldc,
    const float* __restrict__ bias, int K, ushort* As, ushort* Bs)
{
  const ushort* Ab = A + (long)(z >> 3) * sA0 + (long)(z & 7) * sA1;
  const ushort* Bb = B + (long)(z >> 3) * sB0 + (long)(z & 7) * sB1;
  const int m0 = bx * 128;
  const int n0 = by * 128;
  const int tid = threadIdx.x;
  const int lane = tid & 63;
  const int wid = tid >> 6;

  const int c0 = tid;
  const int arow0 = min(m0 + (c0 >> 2), validM - 1);
  const int arow1 = min(m0 + (c0 >> 2) + 64, validM - 1);
  const int brow0 = min(n0 + (c0 >> 2), validN - 1);
  const int brow1 = min(n0 + (c0 >> 2) + 64, validN - 1);
  const int seg = (c0 & 3) * 8;

  const int wr = (wid >> 1) * 64;
  const int wc = (wid & 1) * 64;
  const int frow = lane & 15;
  const int fk = (lane >> 4) * 8;

  f32x4 acc[4][4] = {};

  for (int kt = 0; kt < K; kt += 32) {
    gload16(Ab + (long)arow0 * lda + kt + seg, As + c0 * 8);
    gload16(Ab + (long)arow1 * lda + kt + seg, As + (c0 + 256) * 8);
    gload16(Bb + (long)brow0 * ldb + kt + seg, Bs + c0 * 8);
    gload16(Bb + (long)brow1 * ldb + kt + seg, Bs + (c0 + 256) * 8);
    __syncthreads();

    bf16x8 af[4], bfr[4];
#pragma unroll
    for (int m = 0; m < 4; ++m)
      af[m] = *(const bf16x8*)(As + (wr + m * 16 + frow) * 32 + fk);
#pragma unroll
    for (int n = 0; n < 4; ++n)
      bfr[n] = *(const bf16x8*)(Bs + (wc + n * 16 + frow) * 32 + fk);
#pragma unroll
    for (int m = 0; m < 4; ++m)
#pragma unroll
      for (int n = 0; n < 4; ++n)
        acc[m][n] = MFMA(af[m], bfr[n], acc[m][n]);
    __syncthreads();
  }

  const long cb = (long)(z >> 3) * sC0 + (long)(z & 7) * sC1;
  const int crow = m0 + wr + (lane >> 4) * 4;
  const int ccol = n0 + wc + (lane & 15);
#pragma unroll
  for (int m = 0; m < 4; ++m)
#pragma unroll
    for (int n = 0; n < 4; ++n)
#pragma unroll
      for (int j = 0; j < 4; ++j) {
        int r = crow + m * 16 + j;
        int c = ccol + n * 16;
        if (r < validM && c < validN) {
          float v = acc[m][n][j];
          if (bias) v += bias[c];
          if (C32) C32[cb + (long)r * ldc + c] = v;
          else     C16[cb + (long)r * ldc + c] = f2bf(v);
        }
      }
}

__global__ __launch_bounds__(256) void gemm_bt(
    const ushort* A, long sA0, long sA1, int lda, int validM,
    const ushort* B, long sB0, long sB1, int ldb, int validN,
    float* C32, ushort* C16, long sC0, long sC1, int ldc,
    const float* bias, int K)
{
  __shared__ ushort As[128 * 32];
  __shared__ ushort Bs[128 * 32];
  gemm_bt_body(blockIdx.x, blockIdx.y, blockIdx.z,
               A, sA0, sA1, lda, validM, B, sB0, sB1, ldb, validN,
               C32, C16, sC0, sC1, ldc, bias, K, As, Bs);
}

// Merged Mt+Nt launch: x<10 -> Nt block (bx=x), x>=10 -> Mt block (by=x-10). z=b*8+h.
__global__ __launch_bounds__(256) void gemm_mtnt(
    const ushort* __restrict__ kv_bf, const ushort* __restrict__ WqT,
    const ushort* __restrict__ Wo_bf, ushort* __restrict__ Mt, ushort* __restrict__ Nt)
{
  __shared__ ushort As[128 * 32];
  __shared__ ushort Bs[128 * 32];
  const int x = blockIdx.x, z = blockIdx.z;
  if (x < 10) {
    gemm_bt_body(x, 0, z, Wo_bf, 0, 160, 1280, 1280,
                 kv_bf + 1280, 77L * 2560, 160, 2560, 77,
                 nullptr, Nt, 1280L * 640, 80, 640, nullptr, 160, As, Bs);
  } else {
    gemm_bt_body(0, x - 10, z, kv_bf, 77L * 2560, 160, 2560, 77,
                 WqT, 0, 160, 1280, 1280,
                 nullptr, Mt, 640L * 1280, 77L * 1280, 1280, nullptr, 160, As, Bs);
  }
}

// ---------------- fused scores GEMM + softmax: A direct from hs f32 (fixed) ----------------
// Tile 128 rows x 192 cols (2 heads x 96), 256 thr (4 waves 2Mx2N), z = batch.
// A: reg-staged f32, distance-2 prefetch (two named reg sets, unroll-by-2), cvt via
// v_cvt_pk_bf16_f32, LINEAR ds_write dest (chunk c=tid -> c*8: zero write conflict),
// swizzle carried on the global source (pair involution, same as read side).
// B: gload16, linear dest, pair-swizzled source. vmcnt(7)/(3)/(0) admits B(t)+A(t+1).
__global__ __launch_bounds__(256, 3) void score_softmax(
    const float* __restrict__ hsf, const ushort* __restrict__ Mt,
    ushort* __restrict__ probs)
{
  __shared__ ushort lds[22528];  // staging 2x10240; bounce 4x5632 (after syncthreads)

  const int z = blockIdx.z;
  const int s0 = blockIdx.x * 128;
  const int h0 = blockIdx.y * 2;
  const int tid = threadIdx.x;
  const int lane = tid & 63;
  const int wid = tid >> 6;
  const int wM = wid >> 1;                  // 0..1
  const int wN = wid & 1;                   // 0..1
  const int l15 = lane & 15;
  const int l4 = lane >> 4;

  // A staging: chunks c0=tid, c1=tid+256 (A tile = 512 chunks of 8 bf16).
  // Dest LINEAR: c*8 ushorts. Source: row/slot from pair involution (f32 elems).
  const float* Ag = hsf + ((long)z * 4096 + s0) * 1280;
  int ak0, ak1;
  const int ar0 = pair_src_row(tid, &ak0);
  const int ar1 = pair_src_row(tid + 256, &ak1);
  const long asrc0 = (long)ar0 * 1280 + ak0 * 8;
  const long asrc1 = (long)ar1 * 1280 + ak1 * 8;

  // B staging: 3 gload16 (192 rows x 4 chunks), head-mapped with t clamped to 76
  const ushort* Bg = Mt + (long)z * (640L * 1280);
  long bsrc[3]; int bdst[3];
#pragma unroll
  for (int j = 0; j < 3; ++j) {
    int c = j * 256 + tid, k8;
    int rb = pair_src_row(c, &k8);
    int hh = h0 + (rb >= 96);
    int tt = min(rb - 96 * (rb >= 96), 76);
    bsrc[j] = (long)(hh * 77 + tt) * 1280 + k8 * 8;
    bdst[j] = 4096 + c * 8;
  }

  // fragment offsets (single K=32 slice per step, k8 = l4)
  int aoff[4], boff[6];
#pragma unroll
  for (int m = 0; m < 4; ++m)
    aoff[m] = pair_frag_off(wM * 64 + m * 16 + l15, l4);
#pragma unroll
  for (int n = 0; n < 6; ++n)
    boff[n] = 4096 + pair_frag_off(wN * 96 + n * 16 + l15, l4);

  f32x4 acc[4][6] = {};
  float4 pa0 = {}, pa1 = {}, pa2 = {}, pa3 = {};  // set A
  float4 pb0 = {}, pb1 = {}, pb2 = {}, pb3 = {};  // set B

#define SS_LOADA(S0, S1, S2, S3, kt) { \
    S0 = *(const float4*)(Ag + asrc0 + (kt)); S1 = *(const float4*)(Ag + asrc0 + (kt) + 4); \
    S2 = *(const float4*)(Ag + asrc1 + (kt)); S3 = *(const float4*)(Ag + asrc1 + (kt) + 4); }
#define SS_GLB(bb, kt) { _Pragma("unroll") for (int j = 0; j < 3; ++j) \
    gload16(Bg + bsrc[j] + (kt), &lds[(bb) + bdst[j]]); }
#define SS_CVTW(S0, S1, S2, S3, bb) { uint4 u_; \
    u_.x = cvtpk(S0.x, S0.y); u_.y = cvtpk(S0.z, S0.w); \
    u_.z = cvtpk(S1.x, S1.y); u_.w = cvtpk(S1.z, S1.w); \
    *(uint4*)(&lds[(bb) + tid * 8]) = u_; \
    u_.x = cvtpk(S2.x, S2.y); u_.y = cvtpk(S2.z, S2.w); \
    u_.z = cvtpk(S3.x, S3.y); u_.w = cvtpk(S3.z, S3.w); \
    *(uint4*)(&lds[(bb) + 2048 + tid * 8]) = u_; }

  // One step. Issue A(t+2) into I-set, B(t+1) into nb; cvt C-set (=A(t+1)) into nb.
#define SS_STEP(t, I0, I1, I2, I3, C0, C1, C2, C3) { \
    const int base_ = ((t) & 1) * 10240; \
    const int nb_ = 10240 - base_; \
    if ((t) + 2 < 40) { \
      SS_LOADA(I0, I1, I2, I3, ((t) + 2) * 32) \
      SB(); \
      SS_GLB(nb_, ((t) + 1) * 32) \
      asm volatile("s_waitcnt vmcnt(7)" ::: "memory"); \
    } else if ((t) + 1 < 40) { \
      SS_GLB(nb_, ((t) + 1) * 32) \
      asm volatile("s_waitcnt vmcnt(3)" ::: "memory"); \
    } else { \
      asm volatile("s_waitcnt vmcnt(0)" ::: "memory"); \
    } \
    SB(); BAR(); SB(); \
    bf16x8 av_[4], bv_[6]; \
    _Pragma("unroll") for (int m = 0; m < 4; ++m) av_[m] = *(const bf16x8*)(&lds[base_ + aoff[m]]); \
    _Pragma("unroll") for (int n = 0; n < 6; ++n) bv_[n] = *(const bf16x8*)(&lds[base_ + boff[n]]); \
    __builtin_amdgcn_s_setprio(1); \
    _Pragma("unroll") for (int m = 0; m < 4; ++m) \
      _Pragma("unroll") for (int n = 0; n < 6; ++n) \
        acc[m][n] = MFMA(av_[m], bv_[n], acc[m][n]); \
    __builtin_amdgcn_s_setprio(0); \
    SB(); \
    if ((t) + 1 < 40) { SS_CVTW(C0, C1, C2, C3, nb_) } \
    asm volatile("s_waitcnt lgkmcnt(0)" ::: "memory"); \
    SB(); BAR(); }

  // prologue: A(0)->setA, B(0)->buf0, cvt A(0) into buf0, A(1)->setA
  SS_LOADA(pa0, pa1, pa2, pa3, 0)
  SB();
  SS_GLB(0, 0)
  SB();
  SS_CVTW(pa0, pa1, pa2, pa3, 0)    // compiler waits A(0); B(0) stays in flight
  SS_LOADA(pa0, pa1, pa2, pa3, 32)  // A(1)
  SB();
  asm volatile("s_waitcnt lgkmcnt(0)" ::: "memory");

  for (int tt = 0; tt < 20; ++tt) {
    SS_STEP(2 * tt,     pb0, pb1, pb2, pb3, pa0, pa1, pa2, pa3)
    SS_STEP(2 * tt + 1, pa0, pa1, pa2, pa3, pb0, pb1, pb2, pb3)
  }
#undef SS_STEP
#undef SS_LOADA
#undef SS_GLB
#undef SS_CVTW

  // ---- wave-local softmax over 77 valid cols
#pragma unroll
  for (int m = 0; m < 4; ++m)
#pragma unroll
    for (int j = 0; j < 4; ++j) {
      float mx = -1e30f;
#pragma unroll
      for (int n = 0; n < 6; ++n)
        if (n * 16 + l15 < 77) mx = fmaxf(mx, acc[m][n][j]);
#pragma unroll
      for (int o = 8; o; o >>= 1) mx = fmaxf(mx, __shfl_xor(mx, o));
      float sum = 0.f;
#pragma unroll
      for (int n = 0; n < 6; ++n) {
        float e = (n * 16 + l15 < 77) ? __expf(acc[m][n][j] - mx) : 0.f;
        acc[m][n][j] = e;
        sum += e;
      }
#pragma unroll
      for (int o = 8; o; o >>= 1) sum += __shfl_xor(sum, o);
      float inv = 1.f / sum;
#pragma unroll
      for (int n = 0; n < 6; ++n) acc[m][n][j] *= inv;
    }

  // ---- per-wave LDS bounce ([64][88] us), coalesced probs store
  __syncthreads();
  ushort* pw = lds + wid * 5632;
#pragma unroll
  for (int m = 0; m < 4; ++m)
#pragma unroll
    for (int n = 0; n < 5; ++n)
#pragma unroll
      for (int j = 0; j < 4; ++j)
        pw[(m * 16 + l4 * 4 + j) * 88 + n * 16 + l15] = f2bf(acc[m][n][j]);

  const uint* pw32 = (const uint*)pw;
  uint* probs32 = (uint*)probs;
  const int head = h0 + wN;
  const long sbase = (long)z * 4096 + s0 + wM * 64;
#pragma unroll 4
  for (int k = 0; k < 40; ++k) {
    int f2 = k * 64 + lane;
    int r = f2 / 40;
    int tp = f2 - r * 40;
    probs32[(sbase + r) * 320 + head * 40 + tp] = pw32[r * 44 + tp];
  }
}

// ---------------- output GEMM: 128x128, BK=32, pair-swizzle, 4 blocks/CU ----------------
__global__ __launch_bounds__(256, 4) void gemm_out(
    const ushort* __restrict__ P, const ushort* __restrict__ Nt,
    float* __restrict__ C, const float* __restrict__ bias)
{
  __shared__ ushort lds[17408];  // staging 2x8192; bounce 4x1088 f32 (after syncthreads)

  const int z = blockIdx.z;
  const ushort* Ab = P + (long)z * (4096L * 640) + (long)blockIdx.x * 128 * 640;
  const ushort* Bb = Nt + (long)z * (1280L * 640) + (long)blockIdx.y * 128 * 640;
  const int tid = threadIdx.x;
  const int lane = tid & 63;
  const int wid = tid >> 6;
  const int wM = wid >> 1;   // 0..1
  const int wN = wid & 1;    // 0..1
  const int l15 = lane & 15;
  const int l4 = lane >> 4;

  long asrc[2]; int adst[2], bdst[2];
#pragma unroll
  for (int j = 0; j < 2; ++j) {
    int c = j * 256 + tid, k8;
    int r = pair_src_row(c, &k8);
    asrc[j] = (long)r * 640 + k8 * 8;   // same source pattern for A and B
    adst[j] = c * 8;
    bdst[j] = 4096 + c * 8;
  }

  int aoff[4], boff[4];
#pragma unroll
  for (int m = 0; m < 4; ++m)
    aoff[m] = pair_frag_off(wM * 64 + m * 16 + l15, l4);
#pragma unroll
  for (int n = 0; n < 4; ++n)
    boff[n] = 4096 + pair_frag_off(wN * 64 + n * 16 + l15, l4);

  f32x4 acc[4][4] = {};

#define OG_STAGE(bb, kt) { \
    _Pragma("unroll") for (int j = 0; j < 2; ++j) gload16(Ab + asrc[j] + (kt), &lds[(bb) + adst[j]]); \
    _Pragma("unroll") for (int j = 0; j < 2; ++j) gload16(Bb + asrc[j] + (kt), &lds[(bb) + bdst[j]]); }

  OG_STAGE(0, 0)

  for (int t = 0; t < 20; ++t) {
    const int base = (t & 1) * 8192;
    if (t + 1 < 20) {
      OG_STAGE(8192 - base, (t + 1) * 32)
      asm volatile("s_waitcnt vmcnt(4)" ::: "memory");
    } else {
      asm volatile("s_waitcnt vmcnt(0)" ::: "memory");
    }
    SB(); BAR(); SB();
    bf16x8 av[4], bv[4];
#pragma unroll
    for (int m = 0; m < 4; ++m) av[m] = *(const bf16x8*)(&lds[base + aoff[m]]);
#pragma unroll
    for (int n = 0; n < 4; ++n) bv[n] = *(const bf16x8*)(&lds[base + boff[n]]);
    __builtin_amdgcn_s_setprio(1);
#pragma unroll
    for (int m = 0; m < 4; ++m)
#pragma unroll
      for (int n = 0; n < 4; ++n)
        acc[m][n] = MFMA(av[m], bv[n], acc[m][n]);
    __builtin_amdgcn_s_setprio(0);
    SB(); BAR();
  }
#undef OG_STAGE

  // ---- coalesced C write via per-wave LDS bounce ([16][68] f32)
  __syncthreads();
  float* pw = (float*)lds + wid * 1088;
  const int ccol = blockIdx.y * 128 + wN * 64;
  const float4 bv4 = *(const float4*)(bias + ccol + l15 * 4);
  const long crow0 = (long)z * 4096 + blockIdx.x * 128 + wM * 64;
#pragma unroll
  for (int m = 0; m < 4; ++m) {
#pragma unroll
    for (int n = 0; n < 4; ++n)
#pragma unroll
      for (int j = 0; j < 4; ++j)
        pw[(l4 * 4 + j) * 68 + n * 16 + l15] = acc[m][n][j];
    asm volatile("s_waitcnt lgkmcnt(0)" ::: "memory"); SB();
#pragma unroll
    for (int pass = 0; pass < 4; ++pass) {
      int r = pass * 4 + l4;
      float4 v = *(const float4*)(pw + r * 68 + l15 * 4);
      v.x += bv4.x; v.y += bv4.y; v.z += bv4.z; v.w += bv4.w;
      *(float4*)(C + (crow0 + m * 16 + r) * 1280 + ccol + l15 * 4) = v;
    }
    asm volatile("s_waitcnt lgkmcnt(0)" ::: "memory"); SB();
  }
}

extern "C" void kernel_launch(void* const* d_in, const int* in_sizes, int n_in,
                              void* d_out, int out_size, void* d_ws, size_t ws_size,
                              hipStream_t stream) {
  (void)in_sizes; (void)n_in; (void)out_size; (void)ws_size;
  const float* hs     = (const float*)d_in[0];
  const float* ehs    = (const float*)d_in[1];
  const float* Wq     = (const float*)d_in[2];
  const float* Wk     = (const float*)d_in[3];
  const float* Wv     = (const float*)d_in[4];
  const float* Wo     = (const float*)d_in[5];
  const float* bo     = (const float*)d_in[6];
  const float* q_down = (const float*)d_in[7];
  const float* q_up   = (const float*)d_in[8];
  const float* k_down = (const float*)d_in[9];
  const float* k_up   = (const float*)d_in[10];
  const float* v_down = (const float*)d_in[11];
  const float* v_up   = (const float*)d_in[12];
  const float* o_down = (const float*)d_in[13];
  const float* o_up   = (const float*)d_in[14];

  char* w = (char*)d_ws;
  size_t off = 0;
  auto alloc = [&](size_t b) { char* p = w + off; off = (off + b + 255) & ~(size_t)255; return p; };
  ushort* ehs_bf = (ushort*)alloc(616L * 768 * 2);
  ushort* WqT    = (ushort*)alloc(1280L * 1280 * 2);   // Wq_eff^T * inv_sqrt(DH)
  ushort* Wkv    = (ushort*)alloc(2560L * 768 * 2);    // [Wk_eff; Wv_eff]
  ushort* Wo_bf  = (ushort*)alloc(1280L * 1280 * 2);
  ushort* kv_bf  = (ushort*)alloc(616L * 2560 * 2);    // k | v
  ushort* Mt     = (ushort*)alloc(8L * 640 * 1280 * 2);
  ushort* Nt     = (ushort*)alloc(8L * 1280 * 640 * 2);  // col = h*80+t
  ushort* probs  = (ushort*)alloc(8L * 4096 * 640 * 2);  // col = h*80+t
  float*  outp   = (float*)d_out;
  const float invs = 0.07905694150420949f;  // 1/sqrt(160)

  // weight prep (no hs pass — score_softmax reads f32 hs directly)
  fold_t<<<dim3(20, 20), 256, 0, stream>>>(Wq, q_up, q_down, WqT, invs);
  smalls<<<15271, 256, 0, stream>>>(ehs, ehs_bf,
      Wk, k_up, k_down, Wv, v_up, v_down, Wkv,
      Wo, o_up, o_down, Wo_bf, Nt);
  // fused k|v projection: (616x768)@(768->2560), bf16 out
  gemm_bt<<<dim3(5, 20, 1), 256, 0, stream>>>(ehs_bf, 0, 0, 768, 616,
      Wkv, 0, 0, 768, 2560, nullptr, kv_bf, 0, 0, 2560, nullptr, 768);
  // Mt and Nt in one launch (z = b*8+h)
  gemm_mtnt<<<dim3(20, 1, 64), 256, 0, stream>>>(kv_bf, WqT, Wo_bf, Mt, Nt);
  // fused scores + softmax -> probs bf16 (col = h*80+t), A = hs f32 direct
  score_softmax<<<dim3(32, 4, 8), 256, 0, stream>>>(hs, Mt, probs);
  // out = probs @ Nt^T + bo
  gemm_out<<<dim3(32, 10, 8), 256, 0, stream>>>(probs, Nt, outp, bo);
}

// Round 13
// 277.575 us; speedup vs baseline: 1.1719x; 1.1719x over previous
//
#include <hip/hip_runtime.h>
#include <hip/hip_bf16.h>
#include <stdint.h>

typedef short bf16x8 __attribute__((ext_vector_type(8)));
typedef float f32x4 __attribute__((ext_vector_type(4)));

#define DEVI static __device__ __forceinline__

DEVI ushort f2bf(float f) {
  union { float f; uint32_t u; } v; v.f = f;
  uint32_t u = v.u;
  return (ushort)((u + 0x7fffu + ((u >> 16) & 1u)) >> 16);
}

DEVI void gload16(const void* g, void* l) {
  __builtin_amdgcn_global_load_lds((const __attribute__((address_space(1))) void*)g,
                                   (__attribute__((address_space(3))) void*)l,
                                   16, 0, 0);
}

#define SB() __builtin_amdgcn_sched_barrier(0)
#define BAR() __builtin_amdgcn_s_barrier()
#define MFMA(a, b, c) __builtin_amdgcn_mfma_f32_16x16x32_bf16((a), (b), (c), 0, 0, 0)

// Pair-interleaved 8-slot swizzle for BK=32 tiles (rows of 64B):
// pair-region (r>>1) = 128B with 8 slots of 16B; logical slot s = k8*2 + (r&1),
// physical = s ^ ((r>>1)&7). Identity: pair_frag_off(pair_src_row(c)) == c*8.
DEVI int pair_src_row(int c, int* k8) {       // c = linear chunk index
  int pair = c >> 3;
  int s = (c & 7) ^ (pair & 7);
  *k8 = s >> 1;
  return pair * 2 + (s & 1);
}
DEVI int pair_frag_off(int r, int k8) {       // ushort offset within region
  int p = (k8 * 2 + (r & 1)) ^ ((r >> 1) & 7);
  return (r >> 1) * 64 + p * 8;
}

// ---------------- hs f32->bf16: pure streaming, grid-stride (r9-proven) ----------------
__global__ __launch_bounds__(256) void cvt_hs(const float* __restrict__ in,
                                              ushort* __restrict__ out) {
  const long step = 2048L * 256;
  for (long idx = (long)blockIdx.x * 256 + threadIdx.x; idx < 5242880; idx += step) {
    const float4* p = (const float4*)(in + idx * 8);
    float4 a = p[0], b = p[1];
    union { ushort us[8]; uint4 v; } r;
    r.us[0] = f2bf(a.x); r.us[1] = f2bf(a.y); r.us[2] = f2bf(a.z); r.us[3] = f2bf(a.w);
    r.us[4] = f2bf(b.x); r.us[5] = f2bf(b.y); r.us[6] = f2bf(b.z); r.us[7] = f2bf(b.w);
    *(uint4*)(out + idx * 8) = r.v;
  }
}

// ---------------- Wq fold + transpose via LDS tile (r9-proven) ----------------
__global__ __launch_bounds__(256) void fold_t(
    const float* __restrict__ W, const float* __restrict__ up,
    const float* __restrict__ down, ushort* __restrict__ outT, float scale)
{
  __shared__ ushort tile[64][66];
  const int o0 = blockIdx.x * 64, i0 = blockIdx.y * 64;
  const int lo = threadIdx.x >> 6;
  const int li = threadIdx.x & 63;
#pragma unroll
  for (int r = 0; r < 16; ++r) {
    int o = o0 + r * 4 + lo;
    int i = i0 + li;
    float v = W[(long)o * 1280 + i];
#pragma unroll
    for (int q = 0; q < 4; ++q) v += up[o * 4 + q] * down[q * 1280 + i];
    tile[li][r * 4 + lo] = f2bf(v * scale);
  }
  __syncthreads();
#pragma unroll
  for (int r = 0; r < 16; ++r) {
    int i = i0 + r * 4 + lo;
    outT[(long)i * 1280 + o0 + li] = tile[r * 4 + lo][li];
  }
}

// ---------------- smalls: cvt_ehs | fold Wk/Wv/Wo | Nt pad | Mt pad ----------------
__global__ __launch_bounds__(256) void smalls(
    const float* __restrict__ ehs, ushort* __restrict__ ehs_bf,
    const float* __restrict__ Wk, const float* __restrict__ k_up, const float* __restrict__ k_down,
    const float* __restrict__ Wv, const float* __restrict__ v_up, const float* __restrict__ v_down,
    ushort* __restrict__ Wkv,
    const float* __restrict__ Wo, const float* __restrict__ o_up, const float* __restrict__ o_down,
    ushort* __restrict__ Wo_bf, ushort* __restrict__ Nt, ushort* __restrict__ Mt)
{
  const int b = blockIdx.x;
  const int tid = threadIdx.x;
  if (b < 231) {
    int idx = b * 256 + tid;
    if (idx < 59136) {
      const float4* p = (const float4*)(ehs + (long)idx * 8);
      float4 a = p[0], c = p[1];
      union { ushort us[8]; uint4 v; } r;
      r.us[0] = f2bf(a.x); r.us[1] = f2bf(a.y); r.us[2] = f2bf(a.z); r.us[3] = f2bf(a.w);
      r.us[4] = f2bf(c.x); r.us[5] = f2bf(c.y); r.us[6] = f2bf(c.z); r.us[7] = f2bf(c.w);
      *(uint4*)(ehs_bf + (long)idx * 8) = r.v;
    }
  } else if (b < 4071) {
    int idx = (b - 231) * 256 + tid;
    int o = idx / 768, i = idx - o * 768;
    float v = Wk[idx];
#pragma unroll
    for (int q = 0; q < 4; ++q) v += k_up[o * 4 + q] * k_down[q * 768 + i];
    Wkv[idx] = f2bf(v);
  } else if (b < 7911) {
    int idx = (b - 4071) * 256 + tid;
    int o = idx / 768, i = idx - o * 768;
    float v = Wv[idx];
#pragma unroll
    for (int q = 0; q < 4; ++q) v += v_up[o * 4 + q] * v_down[q * 768 + i];
    Wkv[983040 + idx] = f2bf(v);
  } else if (b < 14311) {
    int idx = (b - 7911) * 256 + tid;
    int o = idx / 1280, i = idx - o * 1280;
    float v = Wo[idx];
#pragma unroll
    for (int q = 0; q < 4; ++q) v += o_up[o * 4 + q] * o_down[q * 1280 + i];
    Wo_bf[idx] = f2bf(v);
  } else if (b < 15271) {                 // Nt pad zero (col = h*80 + 77..79)
    int idx = (b - 14311) * 256 + tid;
    int bb = idx / (1280 * 24);
    int rem = idx % (1280 * 24);
    int j = rem / 24, q = rem % 24;
    int h = q / 3, t = 77 + q % 3;
    Nt[(long)bb * 1280 * 640 + (long)j * 640 + h * 80 + t] = 0;
  } else {                                // Mt pad-row zero (row = h*80 + 77..79)
    int idx = (b - 15271) * 256 + tid;
    int bb = idx / 30720;
    int rem = idx % 30720;
    int h = rem / 3840;
    int q = rem % 3840;
    int p = q / 1280, i = q % 1280;
    Mt[(long)bb * 819200 + (long)(h * 80 + 77 + p) * 1280 + i] = 0;
  }
}

// ---------------- small-GEMM body (128x128, BK=32) — proven ----------------

DEVI void gemm_bt_body(int bx, int by, int z,
    const ushort* __restrict__ A, long sA0, long sA1, int lda, int validM,
    const ushort* __restrict__ B, long sB0, long sB1, int ldb, int validN,
    float* __restrict__ C32, ushort* __restrict__ C16, long sC0, long sC1, int ldc,
    const float* __restrict__ bias, int K, ushort* As, ushort* Bs)
{
  const ushort* Ab = A + (long)(z >> 3) * sA0 + (long)(z & 7) * sA1;
  const ushort* Bb = B + (long)(z >> 3) * sB0 + (long)(z & 7) * sB1;
  const int m0 = bx * 128;
  const int n0 = by * 128;
  const int tid = threadIdx.x;
  const int lane = tid & 63;
  const int wid = tid >> 6;

  const int c0 = tid;
  const int arow0 = min(m0 + (c0 >> 2), validM - 1);
  const int arow1 = min(m0 + (c0 >> 2) + 64, validM - 1);
  const int brow0 = min(n0 + (c0 >> 2), validN - 1);
  const int brow1 = min(n0 + (c0 >> 2) + 64, validN - 1);
  const int seg = (c0 & 3) * 8;

  const int wr = (wid >> 1) * 64;
  const int wc = (wid & 1) * 64;
  const int frow = lane & 15;
  const int fk = (lane >> 4) * 8;

  f32x4 acc[4][4] = {};

  for (int kt = 0; kt < K; kt += 32) {
    gload16(Ab + (long)arow0 * lda + kt + seg, As + c0 * 8);
    gload16(Ab + (long)arow1 * lda + kt + seg, As + (c0 + 256) * 8);
    gload16(Bb + (long)brow0 * ldb + kt + seg, Bs + c0 * 8);
    gload16(Bb + (long)brow1 * ldb + kt + seg, Bs + (c0 + 256) * 8);
    __syncthreads();

    bf16x8 af[4], bfr[4];
#pragma unroll
    for (int m = 0; m < 4; ++m)
      af[m] = *(const bf16x8*)(As + (wr + m * 16 + frow) * 32 + fk);
#pragma unroll
    for (int n = 0; n < 4; ++n)
      bfr[n] = *(const bf16x8*)(Bs + (wc + n * 16 + frow) * 32 + fk);
#pragma unroll
    for (int m = 0; m < 4; ++m)
#pragma unroll
      for (int n = 0; n < 4; ++n)
        acc[m][n] = MFMA(af[m], bfr[n], acc[m][n]);
    __syncthreads();
  }

  const long cb = (long)(z >> 3) * sC0 + (long)(z & 7) * sC1;
  const int crow = m0 + wr + (lane >> 4) * 4;
  const int ccol = n0 + wc + (lane & 15);
#pragma unroll
  for (int m = 0; m < 4; ++m)
#pragma unroll
    for (int n = 0; n < 4; ++n)
#pragma unroll
      for (int j = 0; j < 4; ++j) {
        int r = crow + m * 16 + j;
        int c = ccol + n * 16;
        if (r < validM && c < validN) {
          float v = acc[m][n][j];
          if (bias) v += bias[c];
          if (C32) C32[cb + (long)r * ldc + c] = v;
          else     C16[cb + (long)r * ldc + c] = f2bf(v);
        }
      }
}

__global__ __launch_bounds__(256) void gemm_bt(
    const ushort* A, long sA0, long sA1, int lda, int validM,
    const ushort* B, long sB0, long sB1, int ldb, int validN,
    float* C32, ushort* C16, long sC0, long sC1, int ldc,
    const float* bias, int K)
{
  __shared__ ushort As[128 * 32];
  __shared__ ushort Bs[128 * 32];
  gemm_bt_body(blockIdx.x, blockIdx.y, blockIdx.z,
               A, sA0, sA1, lda, validM, B, sB0, sB1, ldb, validN,
               C32, C16, sC0, sC1, ldc, bias, K, As, Bs);
}

// Merged Mt+Nt launch: x<10 -> Nt block (bx=x), x>=10 -> Mt block (by=x-10). z=b*8+h.
// Mt layout: [b][h*80+t][1280] (pad rows 77..79 pre-zeroed by smalls).
__global__ __launch_bounds__(256) void gemm_mtnt(
    const ushort* __restrict__ kv_bf, const ushort* __restrict__ WqT,
    const ushort* __restrict__ Wo_bf, ushort* __restrict__ Mt, ushort* __restrict__ Nt)
{
  __shared__ ushort As[128 * 32];
  __shared__ ushort Bs[128 * 32];
  const int x = blockIdx.x, z = blockIdx.z;
  if (x < 10) {
    gemm_bt_body(x, 0, z, Wo_bf, 0, 160, 1280, 1280,
                 kv_bf + 1280, 77L * 2560, 160, 2560, 77,
                 nullptr, Nt, 1280L * 640, 80, 640, nullptr, 160, As, Bs);
  } else {
    gemm_bt_body(0, x - 10, z, kv_bf, 77L * 2560, 160, 2560, 77,
                 WqT, 0, 160, 1280, 1280,
                 nullptr, Mt, 819200, 102400, 1280, nullptr, 160, As, Bs);
  }
}

// ---------------- fused scores GEMM + softmax (128x160, BK=32, 3 blocks/CU) ----------------
// Tile 128 hs-rows x 2 heads x 80 cols (ceil(77/16)*16 — no wasted N-tile). z = batch.
// 256 thr, waves 2Mx2N: wave = 64 rows x 80 cols = one head -> wave-local softmax.
// A from hs_bf via gload16 (2 chunks/thr); B from Mt[b][h*80+t][1280] via gload16
// (uniform rows, pad rows pre-zeroed: no clamp). B = 640 chunks = 2.5/thr: waves 0-1
// issue 3 B-loads (vmcnt(5)), waves 2-3 issue 2 (vmcnt(4)) — wave-uniform split.
// Pair-swizzle (linear dest / pre-swizzled source / same involution on reads).
__global__ __launch_bounds__(256, 3) void score_softmax(
    const ushort* __restrict__ hsb, const ushort* __restrict__ Mt,
    ushort* __restrict__ probs)
{
  __shared__ ushort lds[23040];  // staging 2x9216 (A 4096 | B 5120); bounce 4x5760

  const int z = blockIdx.z;
  const int s0 = blockIdx.x * 128;
  const int h0 = blockIdx.y * 2;
  const int tid = threadIdx.x;
  const int lane = tid & 63;
  const int wid = tid >> 6;
  const int wM = wid >> 1;                  // 0..1
  const int wN = wid & 1;                   // 0..1
  const int l15 = lane & 15;
  const int l4 = lane >> 4;
  const bool xb = tid < 128;                // extra-B-loader waves (0,1)

  // A staging: chunks tid, 256+tid (rows 0..127 via pair involution)
  const ushort* Ag = hsb + ((long)z * 4096 + s0) * 1280;
  int ak0, ak1;
  const int ar0 = pair_src_row(tid, &ak0);
  const int ar1 = pair_src_row(tid + 256, &ak1);
  const long asrc0 = (long)ar0 * 1280 + ak0 * 8;
  const long asrc1 = (long)ar1 * 1280 + ak1 * 8;
  // B staging: chunks tid, 256+tid, and (tid<128) 512+tid (rows 0..159)
  const ushort* Bg = Mt + (long)z * 819200 + (long)h0 * 80 * 1280;
  int bk0, bk1, bk2;
  const int br0 = pair_src_row(tid, &bk0);
  const int br1 = pair_src_row(tid + 256, &bk1);
  const int br2 = pair_src_row(tid + 512, &bk2);
  const long bsrc0 = (long)br0 * 1280 + bk0 * 8;
  const long bsrc1 = (long)br1 * 1280 + bk1 * 8;
  const long bsrc2 = (long)br2 * 1280 + bk2 * 8;

  // fragment offsets (single K=32 slice per step, k8 = l4)
  int aoff[4], boff[5];
#pragma unroll
  for (int m = 0; m < 4; ++m)
    aoff[m] = pair_frag_off(wM * 64 + m * 16 + l15, l4);
#pragma unroll
  for (int n = 0; n < 5; ++n)
    boff[n] = 4096 + pair_frag_off(wN * 80 + n * 16 + l15, l4);

  f32x4 acc[4][5] = {};

#define SS_STAGE(bb, kt) { \
    gload16(Ag + asrc0 + (kt), &lds[(bb) + tid * 8]); \
    gload16(Ag + asrc1 + (kt), &lds[(bb) + 2048 + tid * 8]); \
    gload16(Bg + bsrc0 + (kt), &lds[(bb) + 4096 + tid * 8]); \
    gload16(Bg + bsrc1 + (kt), &lds[(bb) + 6144 + tid * 8]); \
    if (xb) gload16(Bg + bsrc2 + (kt), &lds[(bb) + 8192 + tid * 8]); }

  SS_STAGE(0, 0)

  for (int t = 0; t < 40; ++t) {
    const int base = (t & 1) * 9216;
    if (t + 1 < 40) {
      SS_STAGE(9216 - base, (t + 1) * 32)
      if (xb) { asm volatile("s_waitcnt vmcnt(5)" ::: "memory"); }
      else    { asm volatile("s_waitcnt vmcnt(4)" ::: "memory"); }
    } else {
      asm volatile("s_waitcnt vmcnt(0)" ::: "memory");
    }
    SB(); BAR(); SB();
    bf16x8 av[4], bv[5];
#pragma unroll
    for (int m = 0; m < 4; ++m) av[m] = *(const bf16x8*)(&lds[base + aoff[m]]);
#pragma unroll
    for (int n = 0; n < 5; ++n) bv[n] = *(const bf16x8*)(&lds[base + boff[n]]);
    __builtin_amdgcn_s_setprio(1);
#pragma unroll
    for (int m = 0; m < 4; ++m)
#pragma unroll
      for (int n = 0; n < 5; ++n)
        acc[m][n] = MFMA(av[m], bv[n], acc[m][n]);
    __builtin_amdgcn_s_setprio(0);
    SB(); BAR();
  }
#undef SS_STAGE

  // ---- wave-local softmax over 77 valid cols
#pragma unroll
  for (int m = 0; m < 4; ++m)
#pragma unroll
    for (int j = 0; j < 4; ++j) {
      float mx = -1e30f;
#pragma unroll
      for (int n = 0; n < 5; ++n)
        if (n * 16 + l15 < 77) mx = fmaxf(mx, acc[m][n][j]);
#pragma unroll
      for (int o = 8; o; o >>= 1) mx = fmaxf(mx, __shfl_xor(mx, o));
      float sum = 0.f;
#pragma unroll
      for (int n = 0; n < 5; ++n) {
        float e = (n * 16 + l15 < 77) ? __expf(acc[m][n][j] - mx) : 0.f;
        acc[m][n][j] = e;
        sum += e;
      }
#pragma unroll
      for (int o = 8; o; o >>= 1) sum += __shfl_xor(sum, o);
      float inv = 1.f / sum;
#pragma unroll
      for (int n = 0; n < 5; ++n) acc[m][n][j] *= inv;
    }

  // ---- per-wave LDS bounce ([64][90] us, stride 90: 4*90=180dw=20 mod 32 -> mostly 2-way)
  __syncthreads();
  ushort* pw = lds + wid * 5760;
#pragma unroll
  for (int m = 0; m < 4; ++m)
#pragma unroll
    for (int n = 0; n < 5; ++n)
#pragma unroll
      for (int j = 0; j < 4; ++j)
        pw[(m * 16 + l4 * 4 + j) * 90 + n * 16 + l15] = f2bf(acc[m][n][j]);

  const uint* pw32 = (const uint*)pw;
  uint* probs32 = (uint*)probs;
  const int head = h0 + wN;
  const long sbase = (long)z * 4096 + s0 + wM * 64;
#pragma unroll 4
  for (int k = 0; k < 40; ++k) {
    int f2 = k * 64 + lane;
    int r = f2 / 40;
    int tp = f2 - r * 40;
    probs32[(sbase + r) * 320 + head * 40 + tp] = pw32[r * 45 + tp];
  }
}

// ---------------- output GEMM: 128x128, BK=32, pair-swizzle, 4 blocks/CU ----------------
__global__ __launch_bounds__(256, 4) void gemm_out(
    const ushort* __restrict__ P, const ushort* __restrict__ Nt,
    float* __restrict__ C, const float* __restrict__ bias)
{
  __shared__ ushort lds[17408];  // staging 2x8192; bounce 4x1088 f32 (after syncthreads)

  const int z = blockIdx.z;
  const ushort* Ab = P + (long)z * (4096L * 640) + (long)blockIdx.x * 128 * 640;
  const ushort* Bb = Nt + (long)z * (1280L * 640) + (long)blockIdx.y * 128 * 640;
  const int tid = threadIdx.x;
  const int lane = tid & 63;
  const int wid = tid >> 6;
  const int wM = wid >> 1;   // 0..1
  const int wN = wid & 1;    // 0..1
  const int l15 = lane & 15;
  const int l4 = lane >> 4;

  long asrc[2]; int adst[2], bdst[2];
#pragma unroll
  for (int j = 0; j < 2; ++j) {
    int c = j * 256 + tid, k8;
    int r = pair_src_row(c, &k8);
    asrc[j] = (long)r * 640 + k8 * 8;   // same source pattern for A and B
    adst[j] = c * 8;
    bdst[j] = 4096 + c * 8;
  }

  int aoff[4], boff[4];
#pragma unroll
  for (int m = 0; m < 4; ++m)
    aoff[m] = pair_frag_off(wM * 64 + m * 16 + l15, l4);
#pragma unroll
  for (int n = 0; n < 4; ++n)
    boff[n] = 4096 + pair_frag_off(wN * 64 + n * 16 + l15, l4);

  f32x4 acc[4][4] = {};

#define OG_STAGE(bb, kt) { \
    _Pragma("unroll") for (int j = 0; j < 2; ++j) gload16(Ab + asrc[j] + (kt), &lds[(bb) + adst[j]]); \
    _Pragma("unroll") for (int j = 0; j < 2; ++j) gload16(Bb + asrc[j] + (kt), &lds[(bb) + bdst[j]]); }

  OG_STAGE(0, 0)

  for (int t = 0; t < 20; ++t) {
    const int base = (t & 1) * 8192;
    if (t + 1 < 20) {
      OG_STAGE(8192 - base, (t + 1) * 32)
      asm volatile("s_waitcnt vmcnt(4)" ::: "memory");
    } else {
      asm volatile("s_waitcnt vmcnt(0)" ::: "memory");
    }
    SB(); BAR(); SB();
    bf16x8 av[4], bv[4];
#pragma unroll
    for (int m = 0; m < 4; ++m) av[m] = *(const bf16x8*)(&lds[base + aoff[m]]);
#pragma unroll
    for (int n = 0; n < 4; ++n) bv[n] = *(const bf16x8*)(&lds[base + boff[n]]);
    __builtin_amdgcn_s_setprio(1);
#pragma unroll
    for (int m = 0; m < 4; ++m)
#pragma unroll
      for (int n = 0; n < 4; ++n)
        acc[m][n] = MFMA(av[m], bv[n], acc[m][n]);
    __builtin_amdgcn_s_setprio(0);
    SB(); BAR();
  }
#undef OG_STAGE

  // ---- coalesced C write via per-wave LDS bounce ([16][68] f32)
  __syncthreads();
  float* pw = (float*)lds + wid * 1088;
  const int ccol = blockIdx.y * 128 + wN * 64;
  const float4 bv4 = *(const float4*)(bias + ccol + l15 * 4);
  const long crow0 = (long)z * 4096 + blockIdx.x * 128 + wM * 64;
#pragma unroll
  for (int m = 0; m < 4; ++m) {
#pragma unroll
    for (int n = 0; n < 4; ++n)
#pragma unroll
      for (int j = 0; j < 4; ++j)
        pw[(l4 * 4 + j) * 68 + n * 16 + l15] = acc[m][n][j];
    asm volatile("s_waitcnt lgkmcnt(0)" ::: "memory"); SB();
#pragma unroll
    for (int pass = 0; pass < 4; ++pass) {
      int r = pass * 4 + l4;
      float4 v = *(const float4*)(pw + r * 68 + l15 * 4);
      v.x += bv4.x; v.y += bv4.y; v.z += bv4.z; v.w += bv4.w;
      *(float4*)(C + (crow0 + m * 16 + r) * 1280 + ccol + l15 * 4) = v;
    }
    asm volatile("s_waitcnt lgkmcnt(0)" ::: "memory"); SB();
  }
}

extern "C" void kernel_launch(void* const* d_in, const int* in_sizes, int n_in,
                              void* d_out, int out_size, void* d_ws, size_t ws_size,
                              hipStream_t stream) {
  (void)in_sizes; (void)n_in; (void)out_size; (void)ws_size;
  const float* hs     = (const float*)d_in[0];
  const float* ehs    = (const float*)d_in[1];
  const float* Wq     = (const float*)d_in[2];
  const float* Wk     = (const float*)d_in[3];
  const float* Wv     = (const float*)d_in[4];
  const float* Wo     = (const float*)d_in[5];
  const float* bo     = (const float*)d_in[6];
  const float* q_down = (const float*)d_in[7];
  const float* q_up   = (const float*)d_in[8];
  const float* k_down = (const float*)d_in[9];
  const float* k_up   = (const float*)d_in[10];
  const float* v_down = (const float*)d_in[11];
  const float* v_up   = (const float*)d_in[12];
  const float* o_down = (const float*)d_in[13];
  const float* o_up   = (const float*)d_in[14];

  char* w = (char*)d_ws;
  size_t off = 0;
  auto alloc = [&](size_t b) { char* p = w + off; off = (off + b + 255) & ~(size_t)255; return p; };
  ushort* hs_bf  = (ushort*)alloc(32768L * 1280 * 2);
  ushort* ehs_bf = (ushort*)alloc(616L * 768 * 2);
  ushort* WqT    = (ushort*)alloc(1280L * 1280 * 2);   // Wq_eff^T * inv_sqrt(DH)
  ushort* Wkv    = (ushort*)alloc(2560L * 768 * 2);    // [Wk_eff; Wv_eff]
  ushort* Wo_bf  = (ushort*)alloc(1280L * 1280 * 2);
  ushort* kv_bf  = (ushort*)alloc(616L * 2560 * 2);    // k | v
  ushort* Mt     = (ushort*)alloc(8L * 640 * 1280 * 2);  // row = h*80+t (pads zeroed)
  ushort* Nt     = (ushort*)alloc(8L * 1280 * 640 * 2);  // col = h*80+t (pads zeroed)
  ushort* probs  = (ushort*)alloc(8L * 4096 * 640 * 2);  // col = h*80+t
  float*  outp   = (float*)d_out;
  const float invs = 0.07905694150420949f;  // 1/sqrt(160)

  // prep
  cvt_hs<<<2048, 256, 0, stream>>>(hs, hs_bf);
  fold_t<<<dim3(20, 20), 256, 0, stream>>>(Wq, q_up, q_down, WqT, invs);
  smalls<<<16231, 256, 0, stream>>>(ehs, ehs_bf,
      Wk, k_up, k_down, Wv, v_up, v_down, Wkv,
      Wo, o_up, o_down, Wo_bf, Nt, Mt);
  // fused k|v projection: (616x768)@(768->2560), bf16 out
  gemm_bt<<<dim3(5, 20, 1), 256, 0, stream>>>(ehs_bf, 0, 0, 768, 616,
      Wkv, 0, 0, 768, 2560, nullptr, kv_bf, 0, 0, 2560, nullptr, 768);
  // Mt and Nt in one launch (z = b*8+h)
  gemm_mtnt<<<dim3(20, 1, 64), 256, 0, stream>>>(kv_bf, WqT, Wo_bf, Mt, Nt);
  // fused scores + softmax -> probs bf16 (col = h*80+t)
  score_softmax<<<dim3(32, 4, 8), 256, 0, stream>>>(hs_bf, Mt, probs);
  // out = probs @ Nt^T + bo
  gemm_out<<<dim3(32, 10, 8), 256, 0, stream>>>(probs, Nt, outp, bo);
}